// Round 2
// baseline (2038.308 us; speedup 1.0000x reference)
//
#include <hip/hip_runtime.h>

typedef unsigned short u16;
typedef unsigned int u32;

#define HW 256
#define PIX 65536

// workspace byte offsets (all intermediates bf16)
#define WS_Q1   100663296ull
#define WS_K1   134217728ull
#define WS_VP   167772160ull
#define WS_NEED 201326592ull

__device__ __forceinline__ float bu2f(u16 u){ union{u32 i; float f;} x; x.i=((u32)u)<<16; return x.f; }
__device__ __forceinline__ u16 f2bu(float f){ union{float f; u32 i;} x; x.f=f; u32 i=x.i; return (u16)((i + 0x7FFFu + ((i>>16)&1u))>>16); }
__device__ __forceinline__ float sigm(float x){ return 1.0f/(1.0f+__expf(-x)); }

// ---------------- 1x1 qkv conv: [384,128] x [128, B*PIX] ----------------
__global__ __launch_bounds__(256) void k_qkv(const float* __restrict__ x, const float* __restrict__ wqkv,
                                             const float* __restrict__ bqkv, u16* __restrict__ qkv){
  int pid = blockIdx.x * 256 + threadIdx.x;
  int b = pid >> 16, p = pid & (PIX-1);
  const float* xb = x + (size_t)b * 128 * PIX + p;
  float xr[128];
  #pragma unroll
  for (int c = 0; c < 128; ++c) xr[c] = xb[(size_t)c * PIX];
  u16* op = qkv + (size_t)b * 384 * PIX + p;
  for (int o = 0; o < 384; ++o){
    float acc = bqkv[o];
    #pragma unroll
    for (int c = 0; c < 128; ++c) acc = fmaf(wqkv[o*128 + c], xr[c], acc);
    op[(size_t)o * PIX] = f2bu(acc);
  }
}

// ---------------- depthwise 3x3 on q,k + fused row L2-normalize ----------------
// 32768 blocks = (b,which,c,hq), one wave per row, 4 rows per block
__global__ __launch_bounds__(256) void k_dwqk(const u16* __restrict__ qkv,
                                              const float* __restrict__ w_q, const float* __restrict__ b_q,
                                              const float* __restrict__ w_k, const float* __restrict__ b_k,
                                              u16* __restrict__ q1, u16* __restrict__ k1){
  int lane = threadIdx.x & 63, wave = threadIdx.x >> 6;
  int idx = blockIdx.x;
  int hq = idx & 63; idx >>= 6;
  int c  = idx & 127; idx >>= 7;
  int which = idx & 1; int b = idx >> 1;
  int h = hq * 4 + wave;
  const u16* in = qkv + ((size_t)(b*384 + which*128 + c)) * PIX;
  const float* wk = (which ? w_k : w_q) + c*9;
  float bias = (which ? b_k : b_q)[c];
  float acc[4];
  float ss = 0.f;
  #pragma unroll
  for (int s = 0; s < 4; ++s){
    int w = s*64 + lane;
    float a = bias;
    #pragma unroll
    for (int i = 0; i < 3; ++i){
      int hh = h + i - 1;
      if (hh < 0 || hh >= HW) continue;
      const u16* row = in + hh*HW;
      #pragma unroll
      for (int j = 0; j < 3; ++j){
        int ww = w + j - 1;
        if (ww < 0 || ww >= HW) continue;
        a = fmaf(wk[i*3+j], bu2f(row[ww]), a);
      }
    }
    acc[s] = a;
    ss = fmaf(a, a, ss);
  }
  #pragma unroll
  for (int m = 1; m < 64; m <<= 1) ss += __shfl_xor(ss, m, 64);
  float scale = 1.0f / fmaxf(sqrtf(ss), 1e-12f);
  u16* outp = (which ? k1 : q1) + ((size_t)(b*128 + c)) * PIX + h*HW;
  #pragma unroll
  for (int s = 0; s < 4; ++s) outp[s*64 + lane] = f2bu(acc[s] * scale);
}

// ---------------- MDC on v: grouped conv, depthwise conv, sigmoid gate ----------------
// block = (b, g, h); threads = w
__global__ __launch_bounds__(256) void k_mdc(const u16* __restrict__ qkv,
                                             const float* __restrict__ w_v1, const float* __restrict__ b_v1,
                                             const float* __restrict__ w_v2, const float* __restrict__ b_v2,
                                             u16* __restrict__ vp){
  int idx = blockIdx.x;
  int h = idx & 255; idx >>= 8;
  int g = idx & 63; int b = idx >> 6;
  int w = threadIdx.x;
  const u16* vbase = qkv + ((size_t)(b*384 + 256)) * PIX;  // v channels start at 256
  const float* w1 = w_v1 + g*18;
  float b1 = b_v1[g];
  const float* w2 = w_v2 + g*9;
  float b2v = b_v2[g];
  __shared__ float x1s[3][HW];
  #pragma unroll
  for (int rr = 0; rr < 3; ++rr){
    int r = h + rr - 1;
    float v = 0.f;
    if (r >= 0 && r < HW){
      v = b1;
      #pragma unroll
      for (int m = 0; m < 2; ++m){
        const u16* ch = vbase + (size_t)(2*g + m) * PIX;
        #pragma unroll
        for (int i = 0; i < 3; ++i){
          int hh = r + i - 1; if (hh < 0 || hh >= HW) continue;
          #pragma unroll
          for (int j = 0; j < 3; ++j){
            int ww = w + j - 1; if (ww < 0 || ww >= HW) continue;
            v = fmaf(w1[m*9 + i*3 + j], bu2f(ch[hh*HW + ww]), v);
          }
        }
      }
    }
    x1s[rr][w] = v;   // rows outside image are zeros (= x2's zero padding)
  }
  __syncthreads();
  float x2 = b2v;
  #pragma unroll
  for (int i = 0; i < 3; ++i){
    #pragma unroll
    for (int j = 0; j < 3; ++j){
      int ww = w + j - 1; if (ww < 0 || ww >= HW) continue;
      x2 = fmaf(w2[i*3 + j], x1s[i][ww], x2);
    }
  }
  float g1 = sigm(bu2f(vbase[(size_t)g * PIX + h*HW + w]));
  float g2 = sigm(bu2f(vbase[(size_t)(64 + g) * PIX + h*HW + w]));
  vp[((size_t)(b*128 + g)) * PIX + h*HW + w]      = f2bu(g1 * x1s[1][w]);
  vp[((size_t)(b*128 + 64 + g)) * PIX + h*HW + w] = f2bu(g2 * x2);
}

// ---------------- per-(b,c) row attention ----------------
// block = (plane, chunk of 64 q-rows); 1024 blocks x 256 threads
#define QS_STR 68
#define VS_STR 264
#define SM_STR 258
#define ATTN_LDS (256*QS_STR*2*2 + 64*VS_STR*2 + 64*SM_STR*2)  // 136448 B

__global__ __launch_bounds__(256,1) void k_attn(const u16* __restrict__ q1, const u16* __restrict__ k1,
                                                const u16* __restrict__ vp, const float* __restrict__ temp,
                                                u16* __restrict__ out){
  extern __shared__ char smemraw[];
  u16* Qs = (u16*)smemraw;            // [256 w][68]: Qs[w][r]
  u16* Kt = Qs + 256*QS_STR;          // [256 w][68]: Kt[w][g]
  u16* Vs = Kt + 256*QS_STR;          // [64 g][264]: Vs[g][w]
  u16* Sm = Vs + 64*VS_STR;           // [64 r][258]: scores/probs (bf16)
  int t = threadIdx.x;
  int blk = blockIdx.x;
  int plane = blk >> 2, chunk = blk & 3;
  int c = plane & 127;
  const u16* qp  = q1 + (size_t)plane * PIX + chunk*64*HW;
  const u16* kp  = k1 + (size_t)plane * PIX;
  const u16* vpp = vp + (size_t)plane * PIX;
  u16* op = out + (size_t)plane * PIX + chunk*64*HW;
  float tc = temp[c];

  // stage Q transposed: Qs[w][r]
  {
    int w = t;
    #pragma unroll 8
    for (int r = 0; r < 64; ++r) Qs[w*QS_STR + r] = qp[r*HW + w];
  }
  int rg = t >> 4, jg = t & 15;
  int r0 = rg * 4, g0 = jg * 4;

  // ---- scores: S[r][g] = dot_w(q1[r], k1[g]) * temp ----
  for (int gt = 0; gt < 4; ++gt){
    __syncthreads();
    {
      int w = t;
      const u16* kpt = kp + gt*64*HW;
      #pragma unroll 8
      for (int g = 0; g < 64; ++g) Kt[w*QS_STR + g] = kpt[g*HW + w];
    }
    __syncthreads();
    float sacc[4][4];
    #pragma unroll
    for (int a = 0; a < 4; ++a)
      #pragma unroll
      for (int bb = 0; bb < 4; ++bb) sacc[a][bb] = 0.f;
    #pragma unroll 4
    for (int w = 0; w < HW; ++w){
      ushort4 qv = *(const ushort4*)(Qs + w*QS_STR + r0);
      ushort4 kv = *(const ushort4*)(Kt + w*QS_STR + g0);
      float qf[4] = {bu2f(qv.x), bu2f(qv.y), bu2f(qv.z), bu2f(qv.w)};
      float kf[4] = {bu2f(kv.x), bu2f(kv.y), bu2f(kv.z), bu2f(kv.w)};
      #pragma unroll
      for (int a = 0; a < 4; ++a)
        #pragma unroll
        for (int bb = 0; bb < 4; ++bb)
          sacc[a][bb] = fmaf(qf[a], kf[bb], sacc[a][bb]);
    }
    #pragma unroll
    for (int a = 0; a < 4; ++a)
      #pragma unroll
      for (int bb = 0; bb < 4; ++bb)
        Sm[(r0+a)*SM_STR + gt*64 + g0 + bb] = f2bu(sacc[a][bb] * tc);
  }
  __syncthreads();

  // ---- softmax over g (row r handled by 4 threads, 64 g each) ----
  {
    int r = t >> 2, j = t & 3;
    u16* srow = Sm + r*SM_STR + j*64;
    float pv[64];
    float m = -1e30f;
    #pragma unroll
    for (int i = 0; i < 64; ++i){ pv[i] = bu2f(srow[i]); m = fmaxf(m, pv[i]); }
    m = fmaxf(m, __shfl_xor(m, 1, 64));
    m = fmaxf(m, __shfl_xor(m, 2, 64));
    float ssum = 0.f;
    #pragma unroll
    for (int i = 0; i < 64; ++i){ pv[i] = __expf(pv[i] - m); ssum += pv[i]; }
    ssum += __shfl_xor(ssum, 1, 64);
    ssum += __shfl_xor(ssum, 2, 64);
    float inv = 1.0f / ssum;
    #pragma unroll
    for (int i = 0; i < 64; ++i) srow[i] = f2bu(pv[i] * inv);
  }

  // ---- PV: out[r][w] = sum_g P[r][g] * vp[g][w] ----
  float acc[4][16];
  #pragma unroll
  for (int a = 0; a < 4; ++a)
    #pragma unroll
    for (int i = 0; i < 16; ++i) acc[a][i] = 0.f;
  int w0 = jg * 16;
  for (int gt = 0; gt < 4; ++gt){
    __syncthreads();
    {
      const uint4* vsrc = (const uint4*)(vpp + (size_t)gt*64*HW);
      #pragma unroll
      for (int i = 0; i < 8; ++i){
        int ck = t + 256*i;              // 2048 uint4 per 64x256 tile
        int g  = ck >> 5;
        int wo = (ck & 31) * 8;
        *(uint4*)(Vs + g*VS_STR + wo) = vsrc[ck];
      }
    }
    __syncthreads();
    #pragma unroll 2
    for (int g = 0; g < 64; ++g){
      float p[4];
      #pragma unroll
      for (int a = 0; a < 4; ++a) p[a] = bu2f(Sm[(r0+a)*SM_STR + gt*64 + g]);
      const u16* vrow = Vs + g*VS_STR + w0;
      uint4 v0 = *(const uint4*)(vrow);
      uint4 v1 = *(const uint4*)(vrow + 8);
      float vf[16];
      vf[0]=bu2f((u16)(v0.x&0xFFFFu)); vf[1]=bu2f((u16)(v0.x>>16));
      vf[2]=bu2f((u16)(v0.y&0xFFFFu)); vf[3]=bu2f((u16)(v0.y>>16));
      vf[4]=bu2f((u16)(v0.z&0xFFFFu)); vf[5]=bu2f((u16)(v0.z>>16));
      vf[6]=bu2f((u16)(v0.w&0xFFFFu)); vf[7]=bu2f((u16)(v0.w>>16));
      vf[8]=bu2f((u16)(v1.x&0xFFFFu)); vf[9]=bu2f((u16)(v1.x>>16));
      vf[10]=bu2f((u16)(v1.y&0xFFFFu)); vf[11]=bu2f((u16)(v1.y>>16));
      vf[12]=bu2f((u16)(v1.z&0xFFFFu)); vf[13]=bu2f((u16)(v1.z>>16));
      vf[14]=bu2f((u16)(v1.w&0xFFFFu)); vf[15]=bu2f((u16)(v1.w>>16));
      #pragma unroll
      for (int a = 0; a < 4; ++a)
        #pragma unroll
        for (int i = 0; i < 16; ++i)
          acc[a][i] = fmaf(p[a], vf[i], acc[a][i]);
    }
  }
  // write out chunk rows
  #pragma unroll
  for (int a = 0; a < 4; ++a){
    u32 w4[8];
    #pragma unroll
    for (int i = 0; i < 8; ++i)
      w4[i] = (u32)f2bu(acc[a][2*i]) | ((u32)f2bu(acc[a][2*i+1]) << 16);
    *(uint4*)(op + (size_t)(r0+a)*HW + w0)     = make_uint4(w4[0],w4[1],w4[2],w4[3]);
    *(uint4*)(op + (size_t)(r0+a)*HW + w0 + 8) = make_uint4(w4[4],w4[5],w4[6],w4[7]);
  }
}

// ---------------- 1x1 output conv (float out) ----------------
__global__ __launch_bounds__(256) void k_po(const u16* __restrict__ ain, const float* __restrict__ w_po,
                                            const float* __restrict__ b_po, float* __restrict__ out){
  int pid = blockIdx.x * 256 + threadIdx.x;
  int b = pid >> 16, p = pid & (PIX-1);
  const u16* ab = ain + (size_t)b * 128 * PIX + p;
  float ar[128];
  #pragma unroll
  for (int c = 0; c < 128; ++c) ar[c] = bu2f(ab[(size_t)c * PIX]);
  float* ob = out + (size_t)b * 128 * PIX + p;
  for (int o = 0; o < 128; ++o){
    float acc = b_po[o];
    #pragma unroll
    for (int c = 0; c < 128; ++c) acc = fmaf(w_po[o*128 + c], ar[c], acc);
    ob[(size_t)o * PIX] = acc;
  }
}

extern "C" void kernel_launch(void* const* d_in, const int* in_sizes, int n_in,
                              void* d_out, int out_size, void* d_ws, size_t ws_size,
                              hipStream_t stream){
  (void)in_sizes; (void)n_in; (void)out_size;
  if (ws_size < (size_t)WS_NEED) return;  // diagnosable: output stays all-zero (absmax == max|ref|)

  const float* x     = (const float*)d_in[0];
  const float* w_qkv = (const float*)d_in[1];
  const float* b_qkv = (const float*)d_in[2];
  const float* w_q   = (const float*)d_in[3];
  const float* b_q   = (const float*)d_in[4];
  const float* w_k   = (const float*)d_in[5];
  const float* b_k   = (const float*)d_in[6];
  const float* w_v1  = (const float*)d_in[7];
  const float* b_v1  = (const float*)d_in[8];
  const float* w_v2  = (const float*)d_in[9];
  const float* b_v2  = (const float*)d_in[10];
  const float* temp  = (const float*)d_in[11];
  const float* w_po  = (const float*)d_in[12];
  const float* b_po  = (const float*)d_in[13];

  char* ws = (char*)d_ws;
  u16*  qkv = (u16*)ws;
  u16*  q1  = (u16*)(ws + WS_Q1);
  u16*  k1  = (u16*)(ws + WS_K1);
  u16*  vp  = (u16*)(ws + WS_VP);
  u16*  aout = qkv;                 // reuse qkv region after mdc (planes 0..255 only)
  float* out = (float*)d_out;

  k_qkv<<<512, 256, 0, stream>>>(x, w_qkv, b_qkv, qkv);
  k_dwqk<<<32768, 256, 0, stream>>>(qkv, w_q, b_q, w_k, b_k, q1, k1);
  k_mdc<<<32768, 256, 0, stream>>>(qkv, w_v1, b_v1, w_v2, b_v2, vp);
  hipFuncSetAttribute((const void*)k_attn, hipFuncAttributeMaxDynamicSharedMemorySize, ATTN_LDS);
  k_attn<<<1024, 256, ATTN_LDS, stream>>>(q1, k1, vp, temp, aout);
  k_po<<<512, 256, 0, stream>>>(aout, w_po, b_po, out);
}

// Round 3
// 901.945 us; speedup vs baseline: 2.2599x; 2.2599x over previous
//
#include <hip/hip_runtime.h>

typedef unsigned short u16;
typedef unsigned int u32;

#define HW 256
#define PIX 65536

// workspace byte offsets
// [0, 100663296)            : qkv (768 bf16 planes); later reused as attn output aout (256 planes)
// [100663296, 134217728)    : xT (bf16 [B*PIX][128]) -> then q1 -> then aT
// [134217728, 167772160)    : k1
// [167772160, 201326592)    : vp
#define WS_T1   100663296ull
#define WS_K1   134217728ull
#define WS_VP   167772160ull
#define WS_NEED 201326592ull

typedef __attribute__((ext_vector_type(8))) short s8v;   // 8 bf16
typedef __attribute__((ext_vector_type(4))) float f4v;

__device__ __forceinline__ float bu2f(u16 u){ union{u32 i; float f;} x; x.i=((u32)u)<<16; return x.f; }
__device__ __forceinline__ u16 f2bu(float f){ union{float f; u32 i;} x; x.f=f; u32 i=x.i; return (u16)((i + 0x7FFFu + ((i>>16)&1u))>>16); }
__device__ __forceinline__ float sigm(float x){ return 1.0f/(1.0f+__expf(-x)); }
__device__ __forceinline__ u16 cvt_el(float v){ return f2bu(v); }
__device__ __forceinline__ u16 cvt_el(u16 v){ return v; }

// ---------------- transpose-cast: in [128 c][PIX p] (per b) -> outT [b*PIX + p][128 c] bf16 ----------------
// block: 128 c x 64 p; grid (PIX/64, B)
template<typename TIN>
__global__ __launch_bounds__(256) void k_tr(const TIN* __restrict__ in, u16* __restrict__ outT){
  int t = threadIdx.x;
  int b = blockIdx.y;
  int p = blockIdx.x * 64 + (t >> 2);
  int cc = (t & 3) * 32;
  const TIN* ip = in + ((size_t)(b*128 + cc)) * PIX + p;
  u16 vals[32];
  #pragma unroll
  for (int j = 0; j < 32; ++j) vals[j] = cvt_el(ip[(size_t)j * PIX]);
  u16* op = outT + ((size_t)(b * PIX + p)) * 128 + cc;
  u32 w2[16];
  #pragma unroll
  for (int j = 0; j < 16; ++j) w2[j] = (u32)vals[2*j] | ((u32)vals[2*j+1] << 16);
  uint4* o4 = (uint4*)op;
  o4[0] = make_uint4(w2[0], w2[1], w2[2], w2[3]);
  o4[1] = make_uint4(w2[4], w2[5], w2[6], w2[7]);
  o4[2] = make_uint4(w2[8], w2[9], w2[10], w2[11]);
  o4[3] = make_uint4(w2[12], w2[13], w2[14], w2[15]);
}

// ---------------- MFMA GEMM: out[o][p] = sum_c W[o][c] * T[p][c] + bias[o] ----------------
// T: bf16 [B*PIX][128]; W: fp32 [O_total][128]; out: planes [b][O_total][PIX]
// block: 4 waves, 128 pixels; grid (B*PIX/128, O_total/OC)
template<int OC, bool F32>
__global__ __launch_bounds__(256) void k_gemm(const u16* __restrict__ T, const float* __restrict__ Wg,
                                              const float* __restrict__ bias, int O_total,
                                              void* __restrict__ outv){
  __shared__ u16 Wl[OC * 128];
  int t = threadIdx.x;
  int o_base = blockIdx.y * OC;
  // stage weights as bf16, XOR-swizzled (c ^= (o&7)<<3) to kill the 256B-stride bank conflict
  for (int i = t; i < OC * 128; i += 256){
    int o = i >> 7, c = i & 127;
    Wl[(o << 7) | (c ^ ((o & 7) << 3))] = f2bu(Wg[(size_t)(o_base + o) * 128 + c]);
  }
  __syncthreads();

  int wv = t >> 6, l = t & 63;
  int lg = l >> 4, lr = l & 15;
  int p_lin0 = blockIdx.x * 128 + wv * 16;
  int b = p_lin0 >> 16;                 // uniform per block (128 | 65536)
  int p_in0 = (p_lin0 & 65535) + lr;

  // B-fragments: direct coalesced global loads, pinned in regs for the whole kernel
  s8v bf[2][4];
  #pragma unroll
  for (int pt = 0; pt < 2; ++pt){
    const u16* bp = T + (((size_t)(p_lin0 + pt*64 + lr)) << 7) + (lg << 3);
    #pragma unroll
    for (int ks = 0; ks < 4; ++ks)
      bf[pt][ks] = *(const s8v*)(bp + ks * 32);
  }

  for (int ot = 0; ot < OC / 16; ++ot){
    f4v acc0 = {0.f,0.f,0.f,0.f}, acc1 = {0.f,0.f,0.f,0.f};
    int o = (ot << 4) + lr;
    const u16* wl = Wl + (o << 7);
    int sw = (o & 7) << 3;
    #pragma unroll
    for (int ks = 0; ks < 4; ++ks){
      s8v a = *(const s8v*)(wl + ((((ks << 5) + (lg << 3)) ^ sw)));
      acc0 = __builtin_amdgcn_mfma_f32_16x16x32_bf16(a, bf[0][ks], acc0, 0, 0, 0);
      acc1 = __builtin_amdgcn_mfma_f32_16x16x32_bf16(a, bf[1][ks], acc1, 0, 0, 0);
    }
    #pragma unroll
    for (int j = 0; j < 4; ++j){
      int o_row = o_base + (ot << 4) + (lg << 2) + j;
      float bv = bias[o_row];
      size_t base = ((size_t)(b * O_total + o_row)) << 16;
      if (F32){
        float* op = (float*)outv;
        op[base + p_in0]      = acc0[j] + bv;
        op[base + p_in0 + 64] = acc1[j] + bv;
      } else {
        u16* op = (u16*)outv;
        op[base + p_in0]      = f2bu(acc0[j] + bv);
        op[base + p_in0 + 64] = f2bu(acc1[j] + bv);
      }
    }
  }
}

// ---------------- depthwise 3x3 on q,k + fused row L2-normalize ----------------
__global__ __launch_bounds__(256) void k_dwqk(const u16* __restrict__ qkv,
                                              const float* __restrict__ w_q, const float* __restrict__ b_q,
                                              const float* __restrict__ w_k, const float* __restrict__ b_k,
                                              u16* __restrict__ q1, u16* __restrict__ k1){
  int lane = threadIdx.x & 63, wave = threadIdx.x >> 6;
  int idx = blockIdx.x;
  int hq = idx & 63; idx >>= 6;
  int c  = idx & 127; idx >>= 7;
  int which = idx & 1; int b = idx >> 1;
  int h = hq * 4 + wave;
  const u16* in = qkv + ((size_t)(b*384 + which*128 + c)) * PIX;
  const float* wk = (which ? w_k : w_q) + c*9;
  float bias = (which ? b_k : b_q)[c];
  float acc[4];
  float ss = 0.f;
  #pragma unroll
  for (int s = 0; s < 4; ++s){
    int w = s*64 + lane;
    float a = bias;
    #pragma unroll
    for (int i = 0; i < 3; ++i){
      int hh = h + i - 1;
      if (hh < 0 || hh >= HW) continue;
      const u16* row = in + hh*HW;
      #pragma unroll
      for (int j = 0; j < 3; ++j){
        int ww = w + j - 1;
        if (ww < 0 || ww >= HW) continue;
        a = fmaf(wk[i*3+j], bu2f(row[ww]), a);
      }
    }
    acc[s] = a;
    ss = fmaf(a, a, ss);
  }
  #pragma unroll
  for (int m = 1; m < 64; m <<= 1) ss += __shfl_xor(ss, m, 64);
  float scale = 1.0f / fmaxf(sqrtf(ss), 1e-12f);
  u16* outp = (which ? k1 : q1) + ((size_t)(b*128 + c)) * PIX + h*HW;
  #pragma unroll
  for (int s = 0; s < 4; ++s) outp[s*64 + lane] = f2bu(acc[s] * scale);
}

// ---------------- MDC on v ----------------
__global__ __launch_bounds__(256) void k_mdc(const u16* __restrict__ qkv,
                                             const float* __restrict__ w_v1, const float* __restrict__ b_v1,
                                             const float* __restrict__ w_v2, const float* __restrict__ b_v2,
                                             u16* __restrict__ vp){
  int idx = blockIdx.x;
  int h = idx & 255; idx >>= 8;
  int g = idx & 63; int b = idx >> 6;
  int w = threadIdx.x;
  const u16* vbase = qkv + ((size_t)(b*384 + 256)) * PIX;
  const float* w1 = w_v1 + g*18;
  float b1 = b_v1[g];
  const float* w2 = w_v2 + g*9;
  float b2v = b_v2[g];
  __shared__ float x1s[3][HW];
  #pragma unroll
  for (int rr = 0; rr < 3; ++rr){
    int r = h + rr - 1;
    float v = 0.f;
    if (r >= 0 && r < HW){
      v = b1;
      #pragma unroll
      for (int m = 0; m < 2; ++m){
        const u16* ch = vbase + (size_t)(2*g + m) * PIX;
        #pragma unroll
        for (int i = 0; i < 3; ++i){
          int hh = r + i - 1; if (hh < 0 || hh >= HW) continue;
          #pragma unroll
          for (int j = 0; j < 3; ++j){
            int ww = w + j - 1; if (ww < 0 || ww >= HW) continue;
            v = fmaf(w1[m*9 + i*3 + j], bu2f(ch[hh*HW + ww]), v);
          }
        }
      }
    }
    x1s[rr][w] = v;
  }
  __syncthreads();
  float x2 = b2v;
  #pragma unroll
  for (int i = 0; i < 3; ++i){
    #pragma unroll
    for (int j = 0; j < 3; ++j){
      int ww = w + j - 1; if (ww < 0 || ww >= HW) continue;
      x2 = fmaf(w2[i*3 + j], x1s[i][ww], x2);
    }
  }
  float g1 = sigm(bu2f(vbase[(size_t)g * PIX + h*HW + w]));
  float g2 = sigm(bu2f(vbase[(size_t)(64 + g) * PIX + h*HW + w]));
  vp[((size_t)(b*128 + g)) * PIX + h*HW + w]      = f2bu(g1 * x1s[1][w]);
  vp[((size_t)(b*128 + 64 + g)) * PIX + h*HW + w] = f2bu(g2 * x2);
}

// ---------------- per-(b,c) row attention ----------------
#define QS_STR 68
#define VS_STR 264
#define SM_STR 258
#define ATTN_LDS (256*QS_STR*2*2 + 64*VS_STR*2 + 64*SM_STR*2)  // 136448 B

__global__ __launch_bounds__(256,1) void k_attn(const u16* __restrict__ q1, const u16* __restrict__ k1,
                                                const u16* __restrict__ vp, const float* __restrict__ temp,
                                                u16* __restrict__ out){
  extern __shared__ char smemraw[];
  u16* Qs = (u16*)smemraw;
  u16* Kt = Qs + 256*QS_STR;
  u16* Vs = Kt + 256*QS_STR;
  u16* Sm = Vs + 64*VS_STR;
  int t = threadIdx.x;
  int blk = blockIdx.x;
  int plane = blk >> 2, chunk = blk & 3;
  int c = plane & 127;
  const u16* qp  = q1 + (size_t)plane * PIX + chunk*64*HW;
  const u16* kp  = k1 + (size_t)plane * PIX;
  const u16* vpp = vp + (size_t)plane * PIX;
  u16* op = out + (size_t)plane * PIX + chunk*64*HW;
  float tc = temp[c];

  {
    int w = t;
    #pragma unroll 8
    for (int r = 0; r < 64; ++r) Qs[w*QS_STR + r] = qp[r*HW + w];
  }
  int rg = t >> 4, jg = t & 15;
  int r0 = rg * 4, g0 = jg * 4;

  for (int gt = 0; gt < 4; ++gt){
    __syncthreads();
    {
      int w = t;
      const u16* kpt = kp + gt*64*HW;
      #pragma unroll 8
      for (int g = 0; g < 64; ++g) Kt[w*QS_STR + g] = kpt[g*HW + w];
    }
    __syncthreads();
    float sacc[4][4];
    #pragma unroll
    for (int a = 0; a < 4; ++a)
      #pragma unroll
      for (int bb = 0; bb < 4; ++bb) sacc[a][bb] = 0.f;
    #pragma unroll 4
    for (int w = 0; w < HW; ++w){
      ushort4 qv = *(const ushort4*)(Qs + w*QS_STR + r0);
      ushort4 kv = *(const ushort4*)(Kt + w*QS_STR + g0);
      float qf[4] = {bu2f(qv.x), bu2f(qv.y), bu2f(qv.z), bu2f(qv.w)};
      float kf[4] = {bu2f(kv.x), bu2f(kv.y), bu2f(kv.z), bu2f(kv.w)};
      #pragma unroll
      for (int a = 0; a < 4; ++a)
        #pragma unroll
        for (int bb = 0; bb < 4; ++bb)
          sacc[a][bb] = fmaf(qf[a], kf[bb], sacc[a][bb]);
    }
    #pragma unroll
    for (int a = 0; a < 4; ++a)
      #pragma unroll
      for (int bb = 0; bb < 4; ++bb)
        Sm[(r0+a)*SM_STR + gt*64 + g0 + bb] = f2bu(sacc[a][bb] * tc);
  }
  __syncthreads();

  {
    int r = t >> 2, j = t & 3;
    u16* srow = Sm + r*SM_STR + j*64;
    float pv[64];
    float m = -1e30f;
    #pragma unroll
    for (int i = 0; i < 64; ++i){ pv[i] = bu2f(srow[i]); m = fmaxf(m, pv[i]); }
    m = fmaxf(m, __shfl_xor(m, 1, 64));
    m = fmaxf(m, __shfl_xor(m, 2, 64));
    float ssum = 0.f;
    #pragma unroll
    for (int i = 0; i < 64; ++i){ pv[i] = __expf(pv[i] - m); ssum += pv[i]; }
    ssum += __shfl_xor(ssum, 1, 64);
    ssum += __shfl_xor(ssum, 2, 64);
    float inv = 1.0f / ssum;
    #pragma unroll
    for (int i = 0; i < 64; ++i) srow[i] = f2bu(pv[i] * inv);
  }

  float acc[4][16];
  #pragma unroll
  for (int a = 0; a < 4; ++a)
    #pragma unroll
    for (int i = 0; i < 16; ++i) acc[a][i] = 0.f;
  int w0 = jg * 16;
  for (int gt = 0; gt < 4; ++gt){
    __syncthreads();
    {
      const uint4* vsrc = (const uint4*)(vpp + (size_t)gt*64*HW);
      #pragma unroll
      for (int i = 0; i < 8; ++i){
        int ck = t + 256*i;
        int g  = ck >> 5;
        int wo = (ck & 31) * 8;
        *(uint4*)(Vs + g*VS_STR + wo) = vsrc[ck];
      }
    }
    __syncthreads();
    #pragma unroll 2
    for (int g = 0; g < 64; ++g){
      float p[4];
      #pragma unroll
      for (int a = 0; a < 4; ++a) p[a] = bu2f(Sm[(r0+a)*SM_STR + gt*64 + g]);
      const u16* vrow = Vs + g*VS_STR + w0;
      uint4 v0 = *(const uint4*)(vrow);
      uint4 v1 = *(const uint4*)(vrow + 8);
      float vf[16];
      vf[0]=bu2f((u16)(v0.x&0xFFFFu)); vf[1]=bu2f((u16)(v0.x>>16));
      vf[2]=bu2f((u16)(v0.y&0xFFFFu)); vf[3]=bu2f((u16)(v0.y>>16));
      vf[4]=bu2f((u16)(v0.z&0xFFFFu)); vf[5]=bu2f((u16)(v0.z>>16));
      vf[6]=bu2f((u16)(v0.w&0xFFFFu)); vf[7]=bu2f((u16)(v0.w>>16));
      vf[8]=bu2f((u16)(v1.x&0xFFFFu)); vf[9]=bu2f((u16)(v1.x>>16));
      vf[10]=bu2f((u16)(v1.y&0xFFFFu)); vf[11]=bu2f((u16)(v1.y>>16));
      vf[12]=bu2f((u16)(v1.z&0xFFFFu)); vf[13]=bu2f((u16)(v1.z>>16));
      vf[14]=bu2f((u16)(v1.w&0xFFFFu)); vf[15]=bu2f((u16)(v1.w>>16));
      #pragma unroll
      for (int a = 0; a < 4; ++a)
        #pragma unroll
        for (int i = 0; i < 16; ++i)
          acc[a][i] = fmaf(p[a], vf[i], acc[a][i]);
    }
  }
  #pragma unroll
  for (int a = 0; a < 4; ++a){
    u32 w4[8];
    #pragma unroll
    for (int i = 0; i < 8; ++i)
      w4[i] = (u32)f2bu(acc[a][2*i]) | ((u32)f2bu(acc[a][2*i+1]) << 16);
    *(uint4*)(op + (size_t)(r0+a)*HW + w0)     = make_uint4(w4[0],w4[1],w4[2],w4[3]);
    *(uint4*)(op + (size_t)(r0+a)*HW + w0 + 8) = make_uint4(w4[4],w4[5],w4[6],w4[7]);
  }
}

extern "C" void kernel_launch(void* const* d_in, const int* in_sizes, int n_in,
                              void* d_out, int out_size, void* d_ws, size_t ws_size,
                              hipStream_t stream){
  (void)in_sizes; (void)n_in; (void)out_size;
  if (ws_size < (size_t)WS_NEED) return;

  const float* x     = (const float*)d_in[0];
  const float* w_qkv = (const float*)d_in[1];
  const float* b_qkv = (const float*)d_in[2];
  const float* w_q   = (const float*)d_in[3];
  const float* b_q   = (const float*)d_in[4];
  const float* w_k   = (const float*)d_in[5];
  const float* b_k   = (const float*)d_in[6];
  const float* w_v1  = (const float*)d_in[7];
  const float* b_v1  = (const float*)d_in[8];
  const float* w_v2  = (const float*)d_in[9];
  const float* b_v2  = (const float*)d_in[10];
  const float* temp  = (const float*)d_in[11];
  const float* w_po  = (const float*)d_in[12];
  const float* b_po  = (const float*)d_in[13];

  char* ws = (char*)d_ws;
  u16*  qkv = (u16*)ws;                 // 768 planes
  u16*  xT  = (u16*)(ws + WS_T1);       // then q1, then aT
  u16*  q1  = (u16*)(ws + WS_T1);
  u16*  k1  = (u16*)(ws + WS_K1);
  u16*  vp  = (u16*)(ws + WS_VP);
  u16*  aout = qkv;                     // attn output (256 planes) over dead qkv
  u16*  aT  = (u16*)(ws + WS_T1);       // transposed attn output over dead q1
  float* out = (float*)d_out;

  k_tr<float><<<dim3(1024, 2), 256, 0, stream>>>(x, xT);
  k_gemm<192, false><<<dim3(1024, 2), 256, 0, stream>>>(xT, w_qkv, b_qkv, 384, (void*)qkv);
  k_dwqk<<<32768, 256, 0, stream>>>(qkv, w_q, b_q, w_k, b_k, q1, k1);
  k_mdc<<<32768, 256, 0, stream>>>(qkv, w_v1, b_v1, w_v2, b_v2, vp);
  hipFuncSetAttribute((const void*)k_attn, hipFuncAttributeMaxDynamicSharedMemorySize, ATTN_LDS);
  k_attn<<<1024, 256, ATTN_LDS, stream>>>(q1, k1, vp, temp, aout);
  k_tr<u16><<<dim3(1024, 2), 256, 0, stream>>>(aout, aT);
  k_gemm<128, true><<<dim3(1024, 1), 256, 0, stream>>>(aT, w_po, b_po, 128, (void*)out);
}

// Round 5
// 532.135 us; speedup vs baseline: 3.8304x; 1.6950x over previous
//
#include <hip/hip_runtime.h>

typedef unsigned short u16;
typedef unsigned int u32;

#define HW 256
#define PIX 65536

// workspace byte offsets
#define WS_T1   100663296ull
#define WS_K1   134217728ull
#define WS_VP   167772160ull
#define WS_NEED 201326592ull

typedef __attribute__((ext_vector_type(8))) short s8v;   // 8 bf16
typedef __attribute__((ext_vector_type(4))) float f4v;

__device__ __forceinline__ float bu2f(u16 u){ union{u32 i; float f;} x; x.i=((u32)u)<<16; return x.f; }
__device__ __forceinline__ u16 f2bu(float f){ union{float f; u32 i;} x; x.f=f; u32 i=x.i; return (u16)((i + 0x7FFFu + ((i>>16)&1u))>>16); }
__device__ __forceinline__ float sigm(float x){ return 1.0f/(1.0f+__expf(-x)); }
__device__ __forceinline__ u16 cvt_el(float v){ return f2bu(v); }
__device__ __forceinline__ u16 cvt_el(u16 v){ return v; }
// XOR swizzle for [R][256] u16 tiles (8-elem block granularity)
__device__ __forceinline__ int swz(int r, int c){ return r*256 + (((c>>3) ^ (r&7))<<3) + (c&7); }

// ---------------- transpose-cast: in [128 c][PIX p] (per b) -> outT [b*PIX + p][128 c] bf16 ----------------
template<typename TIN>
__global__ __launch_bounds__(256) void k_tr(const TIN* __restrict__ in, u16* __restrict__ outT){
  int t = threadIdx.x;
  int b = blockIdx.y;
  int p = blockIdx.x * 64 + (t >> 2);
  int cc = (t & 3) * 32;
  const TIN* ip = in + ((size_t)(b*128 + cc)) * PIX + p;
  u16 vals[32];
  #pragma unroll
  for (int j = 0; j < 32; ++j) vals[j] = cvt_el(ip[(size_t)j * PIX]);
  u16* op = outT + ((size_t)(b * PIX + p)) * 128 + cc;
  u32 w2[16];
  #pragma unroll
  for (int j = 0; j < 16; ++j) w2[j] = (u32)vals[2*j] | ((u32)vals[2*j+1] << 16);
  uint4* o4 = (uint4*)op;
  o4[0] = make_uint4(w2[0], w2[1], w2[2], w2[3]);
  o4[1] = make_uint4(w2[4], w2[5], w2[6], w2[7]);
  o4[2] = make_uint4(w2[8], w2[9], w2[10], w2[11]);
  o4[3] = make_uint4(w2[12], w2[13], w2[14], w2[15]);
}

// ---------------- MFMA GEMM: out[o][p] = sum_c W[o][c] * T[p][c] + bias[o] ----------------
template<int OC, bool F32>
__global__ __launch_bounds__(256) void k_gemm(const u16* __restrict__ T, const float* __restrict__ Wg,
                                              const float* __restrict__ bias, int O_total,
                                              void* __restrict__ outv){
  __shared__ u16 Wl[OC * 128];
  int t = threadIdx.x;
  int o_base = blockIdx.y * OC;
  for (int i = t; i < OC * 128; i += 256){
    int o = i >> 7, c = i & 127;
    Wl[(o << 7) | (c ^ ((o & 7) << 3))] = f2bu(Wg[(size_t)(o_base + o) * 128 + c]);
  }
  __syncthreads();

  int wv = t >> 6, l = t & 63;
  int lg = l >> 4, lr = l & 15;
  int p_lin0 = blockIdx.x * 128 + wv * 16;
  int b = p_lin0 >> 16;
  int p_in0 = (p_lin0 & 65535) + lr;

  s8v bf[2][4];
  #pragma unroll
  for (int pt = 0; pt < 2; ++pt){
    const u16* bp = T + (((size_t)(p_lin0 + pt*64 + lr)) << 7) + (lg << 3);
    #pragma unroll
    for (int ks = 0; ks < 4; ++ks)
      bf[pt][ks] = *(const s8v*)(bp + ks * 32);
  }

  for (int ot = 0; ot < OC / 16; ++ot){
    f4v acc0 = {0.f,0.f,0.f,0.f}, acc1 = {0.f,0.f,0.f,0.f};
    int o = (ot << 4) + lr;
    const u16* wl = Wl + (o << 7);
    int sw = (o & 7) << 3;
    #pragma unroll
    for (int ks = 0; ks < 4; ++ks){
      s8v a = *(const s8v*)(wl + ((((ks << 5) + (lg << 3)) ^ sw)));
      acc0 = __builtin_amdgcn_mfma_f32_16x16x32_bf16(a, bf[0][ks], acc0, 0, 0, 0);
      acc1 = __builtin_amdgcn_mfma_f32_16x16x32_bf16(a, bf[1][ks], acc1, 0, 0, 0);
    }
    #pragma unroll
    for (int j = 0; j < 4; ++j){
      int o_row = o_base + (ot << 4) + (lg << 2) + j;
      float bv = bias[o_row];
      size_t base = ((size_t)(b * O_total + o_row)) << 16;
      if (F32){
        float* op = (float*)outv;
        op[base + p_in0]      = acc0[j] + bv;
        op[base + p_in0 + 64] = acc1[j] + bv;
      } else {
        u16* op = (u16*)outv;
        op[base + p_in0]      = f2bu(acc0[j] + bv);
        op[base + p_in0 + 64] = f2bu(acc1[j] + bv);
      }
    }
  }
}

// ---------------- depthwise 3x3 on q,k + fused row L2-normalize ----------------
__global__ __launch_bounds__(256) void k_dwqk(const u16* __restrict__ qkv,
                                              const float* __restrict__ w_q, const float* __restrict__ b_q,
                                              const float* __restrict__ w_k, const float* __restrict__ b_k,
                                              u16* __restrict__ q1, u16* __restrict__ k1){
  int lane = threadIdx.x & 63, wave = threadIdx.x >> 6;
  int idx = blockIdx.x;
  int hq = idx & 63; idx >>= 6;
  int c  = idx & 127; idx >>= 7;
  int which = idx & 1; int b = idx >> 1;
  int h = hq * 4 + wave;
  const u16* in = qkv + ((size_t)(b*384 + which*128 + c)) * PIX;
  const float* wk = (which ? w_k : w_q) + c*9;
  float bias = (which ? b_k : b_q)[c];
  float acc[4];
  float ss = 0.f;
  #pragma unroll
  for (int s = 0; s < 4; ++s){
    int w = s*64 + lane;
    float a = bias;
    #pragma unroll
    for (int i = 0; i < 3; ++i){
      int hh = h + i - 1;
      if (hh < 0 || hh >= HW) continue;
      const u16* row = in + hh*HW;
      #pragma unroll
      for (int j = 0; j < 3; ++j){
        int ww = w + j - 1;
        if (ww < 0 || ww >= HW) continue;
        a = fmaf(wk[i*3+j], bu2f(row[ww]), a);
      }
    }
    acc[s] = a;
    ss = fmaf(a, a, ss);
  }
  #pragma unroll
  for (int m = 1; m < 64; m <<= 1) ss += __shfl_xor(ss, m, 64);
  float scale = 1.0f / fmaxf(sqrtf(ss), 1e-12f);
  u16* outp = (which ? k1 : q1) + ((size_t)(b*128 + c)) * PIX + h*HW;
  #pragma unroll
  for (int s = 0; s < 4; ++s) outp[s*64 + lane] = f2bu(acc[s] * scale);
}

// ---------------- MDC on v ----------------
__global__ __launch_bounds__(256) void k_mdc(const u16* __restrict__ qkv,
                                             const float* __restrict__ w_v1, const float* __restrict__ b_v1,
                                             const float* __restrict__ w_v2, const float* __restrict__ b_v2,
                                             u16* __restrict__ vp){
  int idx = blockIdx.x;
  int h = idx & 255; idx >>= 8;
  int g = idx & 63; int b = idx >> 6;
  int w = threadIdx.x;
  const u16* vbase = qkv + ((size_t)(b*384 + 256)) * PIX;
  const float* w1 = w_v1 + g*18;
  float b1 = b_v1[g];
  const float* w2 = w_v2 + g*9;
  float b2v = b_v2[g];
  __shared__ float x1s[3][HW];
  #pragma unroll
  for (int rr = 0; rr < 3; ++rr){
    int r = h + rr - 1;
    float v = 0.f;
    if (r >= 0 && r < HW){
      v = b1;
      #pragma unroll
      for (int m = 0; m < 2; ++m){
        const u16* ch = vbase + (size_t)(2*g + m) * PIX;
        #pragma unroll
        for (int i = 0; i < 3; ++i){
          int hh = r + i - 1; if (hh < 0 || hh >= HW) continue;
          #pragma unroll
          for (int j = 0; j < 3; ++j){
            int ww = w + j - 1; if (ww < 0 || ww >= HW) continue;
            v = fmaf(w1[m*9 + i*3 + j], bu2f(ch[hh*HW + ww]), v);
          }
        }
      }
    }
    x1s[rr][w] = v;
  }
  __syncthreads();
  float x2 = b2v;
  #pragma unroll
  for (int i = 0; i < 3; ++i){
    #pragma unroll
    for (int j = 0; j < 3; ++j){
      int ww = w + j - 1; if (ww < 0 || ww >= HW) continue;
      x2 = fmaf(w2[i*3 + j], x1s[i][ww], x2);
    }
  }
  float g1 = sigm(bu2f(vbase[(size_t)g * PIX + h*HW + w]));
  float g2 = sigm(bu2f(vbase[(size_t)(64 + g) * PIX + h*HW + w]));
  vp[((size_t)(b*128 + g)) * PIX + h*HW + w]      = f2bu(g1 * x1s[1][w]);
  vp[((size_t)(b*128 + 64 + g)) * PIX + h*HW + w] = f2bu(g2 * x2);
}

// ---------------- MFMA per-(b,c) row attention ----------------
// block = (plane, half of 128 q-rows); 512 blocks x 512 threads, 160KB LDS
#define AT2_LDS 163840

__global__ __launch_bounds__(512,1) void k_attn2(const u16* __restrict__ q1, const u16* __restrict__ k1,
                                                 const u16* __restrict__ vp, const float* __restrict__ temp,
                                                 u16* __restrict__ out){
  extern __shared__ char smemraw[];
  u16* Qs = (u16*)smemraw;       // [128][256] swz; later Vt[256][64] (w>>3 swz); later Os[128][256] swz
  u16* Ks = Qs + 32768;          // [64][256] swz: K tile, then V tile
  u16* Ps = Ks + 16384;          // [128][256] swz
  const int t = threadIdx.x;
  const int l = t & 63;
  const int wv = t >> 6;
  const int c15 = l & 15, h = l >> 4;
  const int blk = blockIdx.x;
  const int plane = blk >> 1, hf = blk & 1;
  const u16* qp  = q1 + (size_t)plane * PIX + hf*128*HW;
  const u16* kp  = k1 + (size_t)plane * PIX;
  const u16* vpp = vp + (size_t)plane * PIX;
  u16* op = out + (size_t)plane * PIX + hf*128*HW;
  const float tc = temp[plane & 127];

  // ---- stage Q (128x256) + K tile 0 (64x256), swizzled ----
  #pragma unroll
  for (int i = 0; i < 8; ++i){
    int c = t + i*512; int row = c >> 5, bc = (c & 31) << 3;
    *(uint4*)(Qs + swz(row, bc)) = *(const uint4*)(qp + row*HW + bc);
  }
  #pragma unroll
  for (int i = 0; i < 4; ++i){
    int c = t + i*512; int row = c >> 5, bc = (c & 31) << 3;
    *(uint4*)(Ks + swz(row, bc)) = *(const uint4*)(kp + row*HW + bc);
  }
  __syncthreads();

  // ---- A-frags: this wave's 16 Q rows, full k=256 (held in 32 VGPRs) ----
  const int r_a = wv*16 + c15;
  s8v qa[8];
  #pragma unroll
  for (int ks = 0; ks < 8; ++ks)
    qa[ks] = *(const s8v*)(Qs + swz(r_a, ks*32 + h*8));

  f4v sacc[16];
  #pragma unroll
  for (int i = 0; i < 16; ++i) sacc[i] = (f4v){0.f,0.f,0.f,0.f};

  uint4 pf[4];
  // ---- scores: S[16r][256g], K-dim = w ----
  #pragma unroll
  for (int gt = 0; gt < 4; ++gt){
    {  // prefetch next K tile (or V tile 0) into regs
      const u16* src = (gt < 3) ? (kp + (gt+1)*64*HW) : vpp;
      #pragma unroll
      for (int i = 0; i < 4; ++i){
        int c = t + i*512; int row = c >> 5, bc = (c & 31) << 3;
        pf[i] = *(const uint4*)(src + row*HW + bc);
      }
    }
    #pragma unroll
    for (int gi = 0; gi < 4; ++gi){
      f4v acc = sacc[gt*4 + gi];
      #pragma unroll
      for (int ks = 0; ks < 8; ++ks){
        s8v b = *(const s8v*)(Ks + swz(gi*16 + c15, ks*32 + h*8));
        acc = __builtin_amdgcn_mfma_f32_16x16x32_bf16(qa[ks], b, acc, 0, 0, 0);
      }
      sacc[gt*4 + gi] = acc;
    }
    __syncthreads();
    #pragma unroll
    for (int i = 0; i < 4; ++i){
      int c = t + i*512; int row = c >> 5, bc = (c & 31) << 3;
      *(uint4*)(Ks + swz(row, bc)) = pf[i];
    }
    __syncthreads();
  }

  // ---- softmax over g, fully in-register (lane holds 4 rows x 16 tiles) ----
  float mj[4] = {-1e30f,-1e30f,-1e30f,-1e30f};
  #pragma unroll
  for (int i = 0; i < 16; ++i)
    #pragma unroll
    for (int j = 0; j < 4; ++j){
      sacc[i][j] *= tc;
      mj[j] = fmaxf(mj[j], sacc[i][j]);
    }
  #pragma unroll
  for (int j = 0; j < 4; ++j){
    mj[j] = fmaxf(mj[j], __shfl_xor(mj[j], 1, 64));
    mj[j] = fmaxf(mj[j], __shfl_xor(mj[j], 2, 64));
    mj[j] = fmaxf(mj[j], __shfl_xor(mj[j], 4, 64));
    mj[j] = fmaxf(mj[j], __shfl_xor(mj[j], 8, 64));
  }
  float sj[4] = {0.f,0.f,0.f,0.f};
  #pragma unroll
  for (int i = 0; i < 16; ++i)
    #pragma unroll
    for (int j = 0; j < 4; ++j){
      float e = __expf(sacc[i][j] - mj[j]);
      sacc[i][j] = e;
      sj[j] += e;
    }
  #pragma unroll
  for (int j = 0; j < 4; ++j){
    sj[j] += __shfl_xor(sj[j], 1, 64);
    sj[j] += __shfl_xor(sj[j], 2, 64);
    sj[j] += __shfl_xor(sj[j], 4, 64);
    sj[j] += __shfl_xor(sj[j], 8, 64);
    sj[j] = 1.0f / sj[j];
  }
  #pragma unroll
  for (int i = 0; i < 16; ++i)
    #pragma unroll
    for (int j = 0; j < 4; ++j)
      Ps[swz(wv*16 + h*4 + j, i*16 + c15)] = f2bu(sacc[i][j] * sj[j]);
  __syncthreads();

  // ---- PV: out[16r][256w], K-dim = g (4 tiles of 64) ----
  f4v oacc[16];
  #pragma unroll
  for (int i = 0; i < 16; ++i) oacc[i] = (f4v){0.f,0.f,0.f,0.f};

  #pragma unroll
  for (int gt = 0; gt < 4; ++gt){
    if (gt < 3){
      #pragma unroll
      for (int i = 0; i < 4; ++i){
        int c = t + i*512; int row = c >> 5, bc = (c & 31) << 3;
        pf[i] = *(const uint4*)(vpp + (gt+1)*64*HW + row*HW + bc);
      }
    }
    // transpose Vs(Ks) [64g][256w] -> Vt(Qs) [256w][64g], 8x8 per thread, t<256
    if (t < 256){
      int gb = t >> 5, wb = t & 31;
      u32 rr[8][4];
      #pragma unroll
      for (int i = 0; i < 8; ++i){
        uint4 v = *(const uint4*)(Ks + (gb*8 + i)*256 + ((wb ^ i) << 3));
        rr[i][0] = v.x; rr[i][1] = v.y; rr[i][2] = v.z; rr[i][3] = v.w;
      }
      #pragma unroll
      for (int j = 0; j < 8; ++j){
        u32 sel = (j & 1) ? 0x07060302u : 0x05040100u;
        int jh = j >> 1;
        u32 o0 = __builtin_amdgcn_perm(rr[1][jh], rr[0][jh], sel);
        u32 o1 = __builtin_amdgcn_perm(rr[3][jh], rr[2][jh], sel);
        u32 o2 = __builtin_amdgcn_perm(rr[5][jh], rr[4][jh], sel);
        u32 o3 = __builtin_amdgcn_perm(rr[7][jh], rr[6][jh], sel);
        int w = wb*8 + j;
        *(uint4*)(Qs + w*64 + ((gb ^ (wb & 7)) << 3)) = make_uint4(o0, o1, o2, o3);
      }
    }
    __syncthreads();
    if (gt < 3){
      #pragma unroll
      for (int i = 0; i < 4; ++i){
        int c = t + i*512; int row = c >> 5, bc = (c & 31) << 3;
        *(uint4*)(Ks + swz(row, bc)) = pf[i];
      }
    }
    s8v pa[2];
    #pragma unroll
    for (int k2 = 0; k2 < 2; ++k2)
      pa[k2] = *(const s8v*)(Ps + swz(r_a, gt*64 + k2*32 + h*8));
    #pragma unroll
    for (int wt = 0; wt < 16; ++wt){
      f4v acc = oacc[wt];
      #pragma unroll
      for (int k2 = 0; k2 < 2; ++k2){
        int w = wt*16 + c15;
        s8v b = *(const s8v*)(Qs + w*64 + ((((k2 << 2) + h) ^ ((w >> 3) & 7)) << 3));
        acc = __builtin_amdgcn_mfma_f32_16x16x32_bf16(pa[k2], b, acc, 0, 0, 0);
      }
      oacc[wt] = acc;
    }
    __syncthreads();
  }

  // ---- stage output in LDS (Qs region), then coalesced global write ----
  #pragma unroll
  for (int wt = 0; wt < 16; ++wt)
    #pragma unroll
    for (int j = 0; j < 4; ++j)
      Qs[swz(wv*16 + h*4 + j, wt*16 + c15)] = f2bu(oacc[wt][j]);
  __syncthreads();
  #pragma unroll
  for (int i = 0; i < 8; ++i){
    int row = wv*16 + i*2 + (l >> 5);
    int bc = (l & 31) << 3;
    uint4 v = *(const uint4*)(Qs + swz(row, bc));
    *(uint4*)(op + row*HW + bc) = v;
  }
}

extern "C" void kernel_launch(void* const* d_in, const int* in_sizes, int n_in,
                              void* d_out, int out_size, void* d_ws, size_t ws_size,
                              hipStream_t stream){
  (void)in_sizes; (void)n_in; (void)out_size;
  if (ws_size < (size_t)WS_NEED) return;

  const float* x     = (const float*)d_in[0];
  const float* w_qkv = (const float*)d_in[1];
  const float* b_qkv = (const float*)d_in[2];
  const float* w_q   = (const float*)d_in[3];
  const float* b_q   = (const float*)d_in[4];
  const float* w_k   = (const float*)d_in[5];
  const float* b_k   = (const float*)d_in[6];
  const float* w_v1  = (const float*)d_in[7];
  const float* b_v1  = (const float*)d_in[8];
  const float* w_v2  = (const float*)d_in[9];
  const float* b_v2  = (const float*)d_in[10];
  const float* temp  = (const float*)d_in[11];
  const float* w_po  = (const float*)d_in[12];
  const float* b_po  = (const float*)d_in[13];

  char* ws = (char*)d_ws;
  u16*  qkv = (u16*)ws;                 // 768 planes
  u16*  xT  = (u16*)(ws + WS_T1);
  u16*  q1  = (u16*)(ws + WS_T1);
  u16*  k1  = (u16*)(ws + WS_K1);
  u16*  vp  = (u16*)(ws + WS_VP);
  u16*  aout = qkv;                     // attn output over dead qkv
  u16*  aT  = (u16*)(ws + WS_T1);       // transposed attn output over dead q1
  float* out = (float*)d_out;

  k_tr<float><<<dim3(1024, 2), 256, 0, stream>>>(x, xT);
  k_gemm<192, false><<<dim3(1024, 2), 256, 0, stream>>>(xT, w_qkv, b_qkv, 384, (void*)qkv);
  k_dwqk<<<32768, 256, 0, stream>>>(qkv, w_q, b_q, w_k, b_k, q1, k1);
  k_mdc<<<32768, 256, 0, stream>>>(qkv, w_v1, b_v1, w_v2, b_v2, vp);
  (void)hipFuncSetAttribute((const void*)k_attn2, hipFuncAttributeMaxDynamicSharedMemorySize, AT2_LDS);
  k_attn2<<<512, 512, AT2_LDS, stream>>>(q1, k1, vp, temp, aout);
  k_tr<u16><<<dim3(1024, 2), 256, 0, stream>>>(aout, aT);
  k_gemm<128, true><<<dim3(1024, 1), 256, 0, stream>>>(aT, w_po, b_po, 128, (void*)out);
}

// Round 6
// 294.354 us; speedup vs baseline: 6.9247x; 1.8078x over previous
//
#include <hip/hip_runtime.h>

typedef unsigned short u16;
typedef unsigned int u32;

#define HW 256
#define PIX 65536

// workspace byte offsets
#define WS_T1   100663296ull
#define WS_K1   134217728ull
#define WS_VP   167772160ull
#define WS_NEED 201326592ull

typedef __attribute__((ext_vector_type(8))) short s8v;   // 8 bf16
typedef __attribute__((ext_vector_type(4))) float f4v;

__device__ __forceinline__ float bu2f(u16 u){ union{u32 i; float f;} x; x.i=((u32)u)<<16; return x.f; }
__device__ __forceinline__ u16 f2bu(float f){ union{float f; u32 i;} x; x.f=f; u32 i=x.i; return (u16)((i + 0x7FFFu + ((i>>16)&1u))>>16); }
__device__ __forceinline__ float sigm(float x){ return 1.0f/(1.0f+__expf(-x)); }
__device__ __forceinline__ u16 cvt_el(float v){ return f2bu(v); }
__device__ __forceinline__ u16 cvt_el(u16 v){ return v; }
// XOR swizzle for [R][256] u16 tiles (8-elem block granularity)
__device__ __forceinline__ int swz(int r, int c){ return r*256 + (((c>>3) ^ (r&7))<<3) + (c&7); }

// ---------------- transpose-cast: in [128 c][PIX p] (per b) -> outT [b*PIX + p][128 c] bf16 ----------------
template<typename TIN>
__global__ __launch_bounds__(256) void k_tr(const TIN* __restrict__ in, u16* __restrict__ outT){
  int t = threadIdx.x;
  int b = blockIdx.y;
  int p = blockIdx.x * 64 + (t >> 2);
  int cc = (t & 3) * 32;
  const TIN* ip = in + ((size_t)(b*128 + cc)) * PIX + p;
  u16 vals[32];
  #pragma unroll
  for (int j = 0; j < 32; ++j) vals[j] = cvt_el(ip[(size_t)j * PIX]);
  u16* op = outT + ((size_t)(b * PIX + p)) * 128 + cc;
  u32 w2[16];
  #pragma unroll
  for (int j = 0; j < 16; ++j) w2[j] = (u32)vals[2*j] | ((u32)vals[2*j+1] << 16);
  uint4* o4 = (uint4*)op;
  o4[0] = make_uint4(w2[0], w2[1], w2[2], w2[3]);
  o4[1] = make_uint4(w2[4], w2[5], w2[6], w2[7]);
  o4[2] = make_uint4(w2[8], w2[9], w2[10], w2[11]);
  o4[3] = make_uint4(w2[12], w2[13], w2[14], w2[15]);
}

// ---------------- MFMA GEMM: out[o][p] = sum_c W[o][c] * T[p][c] + bias[o] ----------------
template<int OC, bool F32>
__global__ __launch_bounds__(256) void k_gemm(const u16* __restrict__ T, const float* __restrict__ Wg,
                                              const float* __restrict__ bias, int O_total,
                                              void* __restrict__ outv){
  __shared__ u16 Wl[OC * 128];
  int t = threadIdx.x;
  int o_base = blockIdx.y * OC;
  for (int i = t; i < OC * 128; i += 256){
    int o = i >> 7, c = i & 127;
    Wl[(o << 7) | (c ^ ((o & 7) << 3))] = f2bu(Wg[(size_t)(o_base + o) * 128 + c]);
  }
  __syncthreads();

  int wv = t >> 6, l = t & 63;
  int lg = l >> 4, lr = l & 15;
  int p_lin0 = blockIdx.x * 128 + wv * 16;
  int b = p_lin0 >> 16;
  int p_in0 = (p_lin0 & 65535) + lr;

  s8v bf[2][4];
  #pragma unroll
  for (int pt = 0; pt < 2; ++pt){
    const u16* bp = T + (((size_t)(p_lin0 + pt*64 + lr)) << 7) + (lg << 3);
    #pragma unroll
    for (int ks = 0; ks < 4; ++ks)
      bf[pt][ks] = *(const s8v*)(bp + ks * 32);
  }

  for (int ot = 0; ot < OC / 16; ++ot){
    f4v acc0 = {0.f,0.f,0.f,0.f}, acc1 = {0.f,0.f,0.f,0.f};
    int o = (ot << 4) + lr;
    const u16* wl = Wl + (o << 7);
    int sw = (o & 7) << 3;
    #pragma unroll
    for (int ks = 0; ks < 4; ++ks){
      s8v a = *(const s8v*)(wl + ((((ks << 5) + (lg << 3)) ^ sw)));
      acc0 = __builtin_amdgcn_mfma_f32_16x16x32_bf16(a, bf[0][ks], acc0, 0, 0, 0);
      acc1 = __builtin_amdgcn_mfma_f32_16x16x32_bf16(a, bf[1][ks], acc1, 0, 0, 0);
    }
    #pragma unroll
    for (int j = 0; j < 4; ++j){
      int o_row = o_base + (ot << 4) + (lg << 2) + j;
      float bv = bias[o_row];
      size_t base = ((size_t)(b * O_total + o_row)) << 16;
      if (F32){
        float* op = (float*)outv;
        op[base + p_in0]      = acc0[j] + bv;
        op[base + p_in0 + 64] = acc1[j] + bv;
      } else {
        u16* op = (u16*)outv;
        op[base + p_in0]      = f2bu(acc0[j] + bv);
        op[base + p_in0 + 64] = f2bu(acc1[j] + bv);
      }
    }
  }
}

// ---------------- depthwise 3x3 on q,k + fused row L2-normalize (LDS tiled) ----------------
// grid (16 chunks, 128 c, 4 = b*2+which); block 256 = 4 waves, wave per row x 4 rows
__global__ __launch_bounds__(256) void k_dwqk2(const u16* __restrict__ qkv,
                                               const float* __restrict__ w_q, const float* __restrict__ b_q,
                                               const float* __restrict__ w_k, const float* __restrict__ b_k,
                                               u16* __restrict__ q1, u16* __restrict__ k1){
  __shared__ u16 ins[18*272];   // rows chunk*16-1 .. chunk*16+16, col c at idx c+8, pads zero
  int t = threadIdx.x;
  int chunk = blockIdx.x;
  int c = blockIdx.y;
  int which = blockIdx.z & 1, b = blockIdx.z >> 1;
  const u16* in = qkv + ((size_t)(b*384 + which*128 + c)) * PIX;

  // zero pads+halo, then stage interior rows vectorized
  #pragma unroll
  for (int i = t; i < 612; i += 256) ((uint4*)ins)[i] = make_uint4(0,0,0,0);
  __syncthreads();
  int r0 = chunk*16 - 1;
  for (int i = t; i < 576; i += 256){
    int j = i >> 5, k = i & 31;
    int r = r0 + j;
    if (r >= 0 && r < HW)
      *(uint4*)(ins + j*272 + 8 + k*8) = *(const uint4*)(in + r*HW + k*8);
  }
  __syncthreads();

  const float* wk = (which ? w_k : w_q) + c*9;
  float K0=wk[0],K1=wk[1],K2=wk[2],K3=wk[3],K4=wk[4],K5=wk[5],K6=wk[6],K7=wk[7],K8=wk[8];
  float bias = (which ? b_k : b_q)[c];

  int wv = t >> 6, l = t & 63;
  int cb = l * 4;                       // this lane's 4 columns
  float wr[3][6];
  // load LDS window row j into wr[slot]: cols cb-1..cb+4
  auto ldrow = [&](int j, int slot){
    ushort4 m = *(const ushort4*)(ins + j*272 + 8 + cb);
    wr[slot][0] = bu2f(ins[j*272 + 7 + cb]);
    wr[slot][1] = bu2f(m.x); wr[slot][2] = bu2f(m.y);
    wr[slot][3] = bu2f(m.z); wr[slot][4] = bu2f(m.w);
    wr[slot][5] = bu2f(ins[j*272 + 12 + cb]);
  };
  int rb = wv * 4;                      // local output row base (LDS window rows rb+s .. rb+s+2)
  ldrow(rb, 0); ldrow(rb+1, 1);
  u16* outp = (which ? k1 : q1) + ((size_t)(b*128 + c)) * PIX;
  #pragma unroll
  for (int s = 0; s < 4; ++s){
    ldrow(rb + s + 2, (s+2)%3);
    const float* T = wr[s%3];
    const float* M = wr[(s+1)%3];
    const float* Bo = wr[(s+2)%3];
    float o[4]; float ss = 0.f;
    #pragma unroll
    for (int d = 0; d < 4; ++d){
      float a = bias;
      a = fmaf(K0, T[d], a);  a = fmaf(K1, T[d+1], a);  a = fmaf(K2, T[d+2], a);
      a = fmaf(K3, M[d], a);  a = fmaf(K4, M[d+1], a);  a = fmaf(K5, M[d+2], a);
      a = fmaf(K6, Bo[d], a); a = fmaf(K7, Bo[d+1], a); a = fmaf(K8, Bo[d+2], a);
      o[d] = a;
      ss = fmaf(a, a, ss);
    }
    #pragma unroll
    for (int m = 1; m < 64; m <<= 1) ss += __shfl_xor(ss, m, 64);
    float sc = 1.0f / fmaxf(sqrtf(ss), 1e-12f);
    int row = chunk*16 + rb + s;
    ushort4 pk;
    pk.x = f2bu(o[0]*sc); pk.y = f2bu(o[1]*sc); pk.z = f2bu(o[2]*sc); pk.w = f2bu(o[3]*sc);
    *(ushort4*)(outp + row*HW + cb) = pk;
  }
}

// ---------------- MDC on v (LDS tiled, 32-row chunks) ----------------
// grid (8 chunks, 64 g, 2 b); block 256 (thread = column)
#define MDC_LDS (2*36*272*2 + 34*272*4)   // 76160 B

__global__ __launch_bounds__(256,1) void k_mdc2(const u16* __restrict__ qkv,
                                                const float* __restrict__ w_v1, const float* __restrict__ b_v1,
                                                const float* __restrict__ w_v2, const float* __restrict__ b_v2,
                                                u16* __restrict__ vp){
  extern __shared__ char sm[];
  u16*   ins = (u16*)sm;                       // [2 ch][36 rows][272], col c at idx c+8
  float* x1s = (float*)(sm + 2*36*272*2);      // [34 rows][272], col c at idx c+8
  int t = threadIdx.x;
  int chunk = blockIdx.x;
  int g = blockIdx.y;
  int b = blockIdx.z;
  const u16* vbase = qkv + ((size_t)(b*384 + 256)) * PIX;

  // zero everything (pads + halo + x1s), then stage 36 input rows x 2 channels
  #pragma unroll
  for (int i = t; i < 2*36*34; i += 256) ((uint4*)ins)[i] = make_uint4(0,0,0,0);   // 2*36*272*2/16 = 2448
  for (int i = t; i < 34*68; i += 256) ((uint4*)x1s)[i] = make_uint4(0,0,0,0);     // 34*272*4/16 = 2312
  __syncthreads();
  int r0 = chunk*32 - 2;
  #pragma unroll
  for (int ch = 0; ch < 2; ++ch){
    const u16* src = vbase + (size_t)(2*g + ch) * PIX;
    for (int i = t; i < 1152; i += 256){
      int j = i >> 5, k = i & 31;
      int r = r0 + j;
      if (r >= 0 && r < HW)
        *(uint4*)(ins + ch*36*272 + j*272 + 8 + k*8) = *(const uint4*)(src + r*HW + k*8);
    }
  }
  __syncthreads();

  // ---- x1: 34 rows (global chunk*32-1 .. chunk*32+32), thread = column t ----
  float W1[18];
  #pragma unroll
  for (int i = 0; i < 18; ++i) W1[i] = w_v1[g*18 + i];
  float B1 = b_v1[g];
  int cb = t + 8;
  float win[2][3][3];
  #pragma unroll
  for (int ch = 0; ch < 2; ++ch)
    #pragma unroll
    for (int rr = 0; rr < 2; ++rr)
      #pragma unroll
      for (int k = 0; k < 3; ++k)
        win[ch][rr][k] = bu2f(ins[ch*36*272 + rr*272 + cb - 1 + k]);
  #pragma unroll
  for (int j = 0; j < 34; ++j){
    #pragma unroll
    for (int ch = 0; ch < 2; ++ch)
      #pragma unroll
      for (int k = 0; k < 3; ++k)
        win[ch][(j+2)%3][k] = bu2f(ins[ch*36*272 + (j+2)*272 + cb - 1 + k]);
    float v = B1;
    #pragma unroll
    for (int ch = 0; ch < 2; ++ch)
      #pragma unroll
      for (int i = 0; i < 3; ++i)
        #pragma unroll
        for (int k = 0; k < 3; ++k)
          v = fmaf(W1[ch*9 + i*3 + k], win[ch][(j+i)%3][k], v);
    int gr = chunk*32 - 1 + j;
    if (gr >= 0 && gr < HW) x1s[j*272 + cb] = v;
  }
  __syncthreads();

  // ---- x2 + gates + outputs: 32 rows ----
  float W2[9];
  #pragma unroll
  for (int i = 0; i < 9; ++i) W2[i] = w_v2[g*9 + i];
  float B2 = b_v2[g];
  const u16* vg   = vbase + (size_t)g * PIX;
  const u16* vg64 = vbase + (size_t)(64 + g) * PIX;
  u16* out0 = vp + ((size_t)(b*128 + g)) * PIX;
  u16* out1 = vp + ((size_t)(b*128 + 64 + g)) * PIX;
  float xw[3][3];
  #pragma unroll
  for (int rr = 0; rr < 2; ++rr)
    #pragma unroll
    for (int k = 0; k < 3; ++k)
      xw[rr][k] = x1s[rr*272 + cb - 1 + k];
  #pragma unroll
  for (int h = 0; h < 32; ++h){
    #pragma unroll
    for (int k = 0; k < 3; ++k)
      xw[(h+2)%3][k] = x1s[(h+2)*272 + cb - 1 + k];
    float x2 = B2;
    #pragma unroll
    for (int i = 0; i < 3; ++i)
      #pragma unroll
      for (int k = 0; k < 3; ++k)
        x2 = fmaf(W2[i*3 + k], xw[(h+i)%3][k], x2);
    int gr = chunk*32 + h;
    float g1 = sigm(bu2f(vg[gr*HW + t]));
    float g2 = sigm(bu2f(vg64[gr*HW + t]));
    float x1c = xw[(h+1)%3][1];
    out0[gr*HW + t] = f2bu(g1 * x1c);
    out1[gr*HW + t] = f2bu(g2 * x2);
  }
}

// ---------------- MFMA per-(b,c) row attention ----------------
// block = (plane, half of 128 q-rows); 512 blocks x 512 threads, 160KB LDS
#define AT2_LDS 163840

__global__ __launch_bounds__(512,1) void k_attn2(const u16* __restrict__ q1, const u16* __restrict__ k1,
                                                 const u16* __restrict__ vp, const float* __restrict__ temp,
                                                 u16* __restrict__ out){
  extern __shared__ char smemraw[];
  u16* Qs = (u16*)smemraw;       // [128][256] swz; later Vt[256][64] (w>>3 swz); later Os[128][256] swz
  u16* Ks = Qs + 32768;          // [64][256] swz: K tile, then V tile
  u16* Ps = Ks + 16384;          // [128][256] swz
  const int t = threadIdx.x;
  const int l = t & 63;
  const int wv = t >> 6;
  const int c15 = l & 15, h = l >> 4;
  const int blk = blockIdx.x;
  const int plane = blk >> 1, hf = blk & 1;
  const u16* qp  = q1 + (size_t)plane * PIX + hf*128*HW;
  const u16* kp  = k1 + (size_t)plane * PIX;
  const u16* vpp = vp + (size_t)plane * PIX;
  u16* op = out + (size_t)plane * PIX + hf*128*HW;
  const float tc = temp[plane & 127];

  // ---- stage Q (128x256) + K tile 0 (64x256), swizzled ----
  #pragma unroll
  for (int i = 0; i < 8; ++i){
    int c = t + i*512; int row = c >> 5, bc = (c & 31) << 3;
    *(uint4*)(Qs + swz(row, bc)) = *(const uint4*)(qp + row*HW + bc);
  }
  #pragma unroll
  for (int i = 0; i < 4; ++i){
    int c = t + i*512; int row = c >> 5, bc = (c & 31) << 3;
    *(uint4*)(Ks + swz(row, bc)) = *(const uint4*)(kp + row*HW + bc);
  }
  __syncthreads();

  // ---- A-frags: this wave's 16 Q rows, full k=256 (held in 32 VGPRs) ----
  const int r_a = wv*16 + c15;
  s8v qa[8];
  #pragma unroll
  for (int ks = 0; ks < 8; ++ks)
    qa[ks] = *(const s8v*)(Qs + swz(r_a, ks*32 + h*8));

  f4v sacc[16];
  #pragma unroll
  for (int i = 0; i < 16; ++i) sacc[i] = (f4v){0.f,0.f,0.f,0.f};

  uint4 pf[4];
  // ---- scores: S[16r][256g], K-dim = w ----
  #pragma unroll
  for (int gt = 0; gt < 4; ++gt){
    {  // prefetch next K tile (or V tile 0) into regs
      const u16* src = (gt < 3) ? (kp + (gt+1)*64*HW) : vpp;
      #pragma unroll
      for (int i = 0; i < 4; ++i){
        int c = t + i*512; int row = c >> 5, bc = (c & 31) << 3;
        pf[i] = *(const uint4*)(src + row*HW + bc);
      }
    }
    #pragma unroll
    for (int gi = 0; gi < 4; ++gi){
      f4v acc = sacc[gt*4 + gi];
      #pragma unroll
      for (int ks = 0; ks < 8; ++ks){
        s8v b = *(const s8v*)(Ks + swz(gi*16 + c15, ks*32 + h*8));
        acc = __builtin_amdgcn_mfma_f32_16x16x32_bf16(qa[ks], b, acc, 0, 0, 0);
      }
      sacc[gt*4 + gi] = acc;
    }
    __syncthreads();
    #pragma unroll
    for (int i = 0; i < 4; ++i){
      int c = t + i*512; int row = c >> 5, bc = (c & 31) << 3;
      *(uint4*)(Ks + swz(row, bc)) = pf[i];
    }
    __syncthreads();
  }

  // ---- softmax over g, fully in-register (lane holds 4 rows x 16 tiles) ----
  float mj[4] = {-1e30f,-1e30f,-1e30f,-1e30f};
  #pragma unroll
  for (int i = 0; i < 16; ++i)
    #pragma unroll
    for (int j = 0; j < 4; ++j){
      sacc[i][j] *= tc;
      mj[j] = fmaxf(mj[j], sacc[i][j]);
    }
  #pragma unroll
  for (int j = 0; j < 4; ++j){
    mj[j] = fmaxf(mj[j], __shfl_xor(mj[j], 1, 64));
    mj[j] = fmaxf(mj[j], __shfl_xor(mj[j], 2, 64));
    mj[j] = fmaxf(mj[j], __shfl_xor(mj[j], 4, 64));
    mj[j] = fmaxf(mj[j], __shfl_xor(mj[j], 8, 64));
  }
  float sj[4] = {0.f,0.f,0.f,0.f};
  #pragma unroll
  for (int i = 0; i < 16; ++i)
    #pragma unroll
    for (int j = 0; j < 4; ++j){
      float e = __expf(sacc[i][j] - mj[j]);
      sacc[i][j] = e;
      sj[j] += e;
    }
  #pragma unroll
  for (int j = 0; j < 4; ++j){
    sj[j] += __shfl_xor(sj[j], 1, 64);
    sj[j] += __shfl_xor(sj[j], 2, 64);
    sj[j] += __shfl_xor(sj[j], 4, 64);
    sj[j] += __shfl_xor(sj[j], 8, 64);
    sj[j] = 1.0f / sj[j];
  }
  #pragma unroll
  for (int i = 0; i < 16; ++i)
    #pragma unroll
    for (int j = 0; j < 4; ++j)
      Ps[swz(wv*16 + h*4 + j, i*16 + c15)] = f2bu(sacc[i][j] * sj[j]);
  __syncthreads();

  // ---- PV: out[16r][256w], K-dim = g (4 tiles of 64) ----
  f4v oacc[16];
  #pragma unroll
  for (int i = 0; i < 16; ++i) oacc[i] = (f4v){0.f,0.f,0.f,0.f};

  #pragma unroll
  for (int gt = 0; gt < 4; ++gt){
    if (gt < 3){
      #pragma unroll
      for (int i = 0; i < 4; ++i){
        int c = t + i*512; int row = c >> 5, bc = (c & 31) << 3;
        pf[i] = *(const uint4*)(vpp + (gt+1)*64*HW + row*HW + bc);
      }
    }
    // transpose Vs(Ks) [64g][256w] -> Vt(Qs) [256w][64g], 8x8 per thread, t<256
    if (t < 256){
      int gb = t >> 5, wb = t & 31;
      u32 rr[8][4];
      #pragma unroll
      for (int i = 0; i < 8; ++i){
        uint4 v = *(const uint4*)(Ks + (gb*8 + i)*256 + ((wb ^ i) << 3));
        rr[i][0] = v.x; rr[i][1] = v.y; rr[i][2] = v.z; rr[i][3] = v.w;
      }
      #pragma unroll
      for (int j = 0; j < 8; ++j){
        u32 sel = (j & 1) ? 0x07060302u : 0x05040100u;
        int jh = j >> 1;
        u32 o0 = __builtin_amdgcn_perm(rr[1][jh], rr[0][jh], sel);
        u32 o1 = __builtin_amdgcn_perm(rr[3][jh], rr[2][jh], sel);
        u32 o2 = __builtin_amdgcn_perm(rr[5][jh], rr[4][jh], sel);
        u32 o3 = __builtin_amdgcn_perm(rr[7][jh], rr[6][jh], sel);
        int w = wb*8 + j;
        *(uint4*)(Qs + w*64 + ((gb ^ (wb & 7)) << 3)) = make_uint4(o0, o1, o2, o3);
      }
    }
    __syncthreads();
    if (gt < 3){
      #pragma unroll
      for (int i = 0; i < 4; ++i){
        int c = t + i*512; int row = c >> 5, bc = (c & 31) << 3;
        *(uint4*)(Ks + swz(row, bc)) = pf[i];
      }
    }
    s8v pa[2];
    #pragma unroll
    for (int k2 = 0; k2 < 2; ++k2)
      pa[k2] = *(const s8v*)(Ps + swz(r_a, gt*64 + k2*32 + h*8));
    #pragma unroll
    for (int wt = 0; wt < 16; ++wt){
      f4v acc = oacc[wt];
      #pragma unroll
      for (int k2 = 0; k2 < 2; ++k2){
        int w = wt*16 + c15;
        s8v b = *(const s8v*)(Qs + w*64 + ((((k2 << 2) + h) ^ ((w >> 3) & 7)) << 3));
        acc = __builtin_amdgcn_mfma_f32_16x16x32_bf16(pa[k2], b, acc, 0, 0, 0);
      }
      oacc[wt] = acc;
    }
    __syncthreads();
  }

  // ---- stage output in LDS (Qs region), then coalesced global write ----
  #pragma unroll
  for (int wt = 0; wt < 16; ++wt)
    #pragma unroll
    for (int j = 0; j < 4; ++j)
      Qs[swz(wv*16 + h*4 + j, wt*16 + c15)] = f2bu(oacc[wt][j]);
  __syncthreads();
  #pragma unroll
  for (int i = 0; i < 8; ++i){
    int row = wv*16 + i*2 + (l >> 5);
    int bc = (l & 31) << 3;
    uint4 v = *(const uint4*)(Qs + swz(row, bc));
    *(uint4*)(op + row*HW + bc) = v;
  }
}

extern "C" void kernel_launch(void* const* d_in, const int* in_sizes, int n_in,
                              void* d_out, int out_size, void* d_ws, size_t ws_size,
                              hipStream_t stream){
  (void)in_sizes; (void)n_in; (void)out_size;
  if (ws_size < (size_t)WS_NEED) return;

  const float* x     = (const float*)d_in[0];
  const float* w_qkv = (const float*)d_in[1];
  const float* b_qkv = (const float*)d_in[2];
  const float* w_q   = (const float*)d_in[3];
  const float* b_q   = (const float*)d_in[4];
  const float* w_k   = (const float*)d_in[5];
  const float* b_k   = (const float*)d_in[6];
  const float* w_v1  = (const float*)d_in[7];
  const float* b_v1  = (const float*)d_in[8];
  const float* w_v2  = (const float*)d_in[9];
  const float* b_v2  = (const float*)d_in[10];
  const float* temp  = (const float*)d_in[11];
  const float* w_po  = (const float*)d_in[12];
  const float* b_po  = (const float*)d_in[13];

  char* ws = (char*)d_ws;
  u16*  qkv = (u16*)ws;                 // 768 planes
  u16*  xT  = (u16*)(ws + WS_T1);
  u16*  q1  = (u16*)(ws + WS_T1);
  u16*  k1  = (u16*)(ws + WS_K1);
  u16*  vp  = (u16*)(ws + WS_VP);
  u16*  aout = qkv;                     // attn output over dead qkv
  u16*  aT  = (u16*)(ws + WS_T1);       // transposed attn output over dead q1
  float* out = (float*)d_out;

  k_tr<float><<<dim3(1024, 2), 256, 0, stream>>>(x, xT);
  k_gemm<192, false><<<dim3(1024, 2), 256, 0, stream>>>(xT, w_qkv, b_qkv, 384, (void*)qkv);
  k_dwqk2<<<dim3(16, 128, 4), 256, 0, stream>>>(qkv, w_q, b_q, w_k, b_k, q1, k1);
  (void)hipFuncSetAttribute((const void*)k_mdc2, hipFuncAttributeMaxDynamicSharedMemorySize, MDC_LDS);
  k_mdc2<<<dim3(8, 64, 2), 256, MDC_LDS, stream>>>(qkv, w_v1, b_v1, w_v2, b_v2, vp);
  (void)hipFuncSetAttribute((const void*)k_attn2, hipFuncAttributeMaxDynamicSharedMemorySize, AT2_LDS);
  k_attn2<<<512, 512, AT2_LDS, stream>>>(q1, k1, vp, temp, aout);
  k_tr<u16><<<dim3(1024, 2), 256, 0, stream>>>(aout, aT);
  k_gemm<128, true><<<dim3(1024, 1), 256, 0, stream>>>(aT, w_po, b_po, 128, (void*)out);
}